// Round 1
// baseline (287.399 us; speedup 1.0000x reference)
//
#include <hip/hip_runtime.h>
#include <hip/hip_bf16.h>
#include <math.h>

typedef unsigned short ushort_t;
typedef __attribute__((ext_vector_type(8))) __bf16 bf16x8;
typedef __attribute__((ext_vector_type(4))) float f32x4;
typedef __attribute__((ext_vector_type(16))) float f32x16;
typedef __attribute__((ext_vector_type(4))) unsigned int u32x4;

#define E_DIM 512
#define HEADS 8
#define HD 64
#define SEQ 2048
#define NROWS 8192        // B * SEQ
#define NEGF (-1e30f)
#define QSCALE 0.18033688011112042f   // 0.125 * log2(e): scores in log2 domain

static __device__ __forceinline__ unsigned short f2b(float f) {
  unsigned int x;
  __builtin_memcpy(&x, &f, 4);
  x += 0x7fffu + ((x >> 16) & 1u);   // RNE (cold epilogues only)
  return (unsigned short)(x >> 16);
}

// v_cvt_pk_bf16_f32: pack 2 f32 -> 2 bf16 (RNE) in one u32. No builtin on gfx950.
static __device__ __forceinline__ unsigned cvt_pk_bf16(float lo, float hi) {
  unsigned r;
  asm("v_cvt_pk_bf16_f32 %0, %1, %2" : "=v"(r) : "v"(lo), "v"(hi));
  return r;
}

// XOR-swizzled LDS index for 64-col bf16 tiles (16B chunks) — conflict-free reads.
static __device__ __forceinline__ int swz(int row, int col) {
  return row * 64 + ((((col >> 3) ^ (row & 7)) & 7) << 3) + (col & 7);
}

// Async 16B/lane global->LDS DMA; dest = lds_base + lane*16B (wave-uniform base).
// Caller realizes the swizzle by permuting the per-lane GLOBAL address.
static __device__ __forceinline__ void gl2lds16(const ushort_t* g, ushort_t* s) {
#if __has_builtin(__builtin_amdgcn_global_load_lds)
  __builtin_amdgcn_global_load_lds(
      (const __attribute__((address_space(1))) unsigned int*)(uintptr_t)g,
      (__attribute__((address_space(3))) unsigned int*)(uintptr_t)s,
      16, 0, 0);
#else
  int l = threadIdx.x & 63;
  *(u32x4*)(s + l * 8) = *(const u32x4*)g;
#endif
}

// ---------------- prep: fused transposeW(x4) + pack_mask + 2x LayerNorm ----------------
__launch_bounds__(256)
__global__ void prep_kernel(const float* __restrict__ Wq, const float* __restrict__ Wk,
                            const float* __restrict__ Wv, const float* __restrict__ Wo,
                            ushort_t* __restrict__ WT,
                            const int* __restrict__ kvm, const int* __restrict__ sp,
                            unsigned long long* __restrict__ bits,
                            const float* __restrict__ xq, const float* __restrict__ xkv,
                            const float* __restrict__ gq, const float* __restrict__ bq,
                            const float* __restrict__ gkv, const float* __restrict__ bkv,
                            ushort_t* __restrict__ yq, ushort_t* __restrict__ ykv) {
  int blk = blockIdx.x;
  int t = threadIdx.x;
  if (blk < 1024) {                       // ---- weight transpose+cast
    int z = blk >> 8, rem = blk & 255;
    const float* in = (z == 0) ? Wq : (z == 1) ? Wk : (z == 2) ? Wv : Wo;
    ushort_t* o = WT + (size_t)z * E_DIM * E_DIM;
    __shared__ float tile[32 * 33];
    int tx = t & 31, ty = t >> 5;
    int n0 = (rem & 15) * 32, k0 = (rem >> 4) * 32;
#pragma unroll
    for (int i = 0; i < 4; ++i) {
      int k = ty + i * 8;
      tile[k * 33 + tx] = in[(k0 + k) * E_DIM + n0 + tx];
    }
    __syncthreads();
#pragma unroll
    for (int i = 0; i < 4; ++i) {
      int n = ty + i * 8;
      o[(n0 + n) * E_DIM + k0 + tx] = f2b(tile[tx * 33 + n]);
    }
  } else if (blk < 3072) {                // ---- mask pack (ballot, coalesced)
    int w = t >> 6, l = t & 63;
    int row = (blk - 1024) * 4 + w;
    int b = row >> 11;
    const int* sprow = sp + ((size_t)row << 11);
    const int* kvrow = kvm + (b << 11);
    unsigned long long* out = bits + ((size_t)row << 5);
#pragma unroll 4
    for (int it = 0; it < 32; ++it) {
      int k = it * 64 + l;
      unsigned long long m = __ballot(sprow[k] != 0 && kvrow[k] != 0);
      if (l == 0) out[it] = m;
    }
  } else {                                // ---- LayerNorm, both tensors
    int idx = blk - 3072;
    int which = idx >> 11;
    const float* x = which ? xkv : xq;
    const float* g = which ? gkv : gq;
    const float* bb = which ? bkv : bq;
    ushort_t* y = which ? ykv : yq;
    int w = t >> 6, l = t & 63;
    int row = (idx & 2047) * 4 + w;
    f32x4 x0 = *(const f32x4*)&x[row * E_DIM + l * 8];
    f32x4 x1 = *(const f32x4*)&x[row * E_DIM + l * 8 + 4];
    float xf[8], s = 0.f, ss = 0.f;
#pragma unroll
    for (int j = 0; j < 8; ++j) {
      xf[j] = (j < 4) ? x0[j] : x1[j - 4];
      s += xf[j];
      ss += xf[j] * xf[j];
    }
#pragma unroll
    for (int off = 32; off > 0; off >>= 1) {
      s += __shfl_xor(s, off);
      ss += __shfl_xor(ss, off);
    }
    float mu = s * (1.f / 512.f);
    float var = fmaxf(ss * (1.f / 512.f) - mu * mu, 0.f);
    float rs = rsqrtf(var + 1e-5f);
    f32x4 g0 = *(const f32x4*)&g[l * 8];
    f32x4 g1 = *(const f32x4*)&g[l * 8 + 4];
    f32x4 b0 = *(const f32x4*)&bb[l * 8];
    f32x4 b1 = *(const f32x4*)&bb[l * 8 + 4];
#pragma unroll
    for (int j = 0; j < 8; ++j) {
      float gv = (j < 4) ? g0[j] : g1[j - 4];
      float bv = (j < 4) ? b0[j] : b1[j - 4];
      y[row * E_DIM + l * 8 + j] = f2b((xf[j] - mu) * rs * gv + bv);
    }
  }
}

// ---------------- GEMM core, 128x128 tile, BK=64, 4 waves in 2x2 (each 64x64) --------------
// MODE 0: bf16 row-major C (with scale)  MODE 1: fp32 row-major C
// MODE 2: bf16 Vt-transposed epilogue  Vt[((b*8+h)*64+d)*2048 + k]  (packed uint2 along k)
template <int MODE>
static __device__ __forceinline__ void gemm_core128(ushort_t* lA, ushort_t* lB,
                                                    const ushort_t* __restrict__ A,
                                                    const ushort_t* __restrict__ WT,
                                                    const float* __restrict__ bias,
                                                    void* Cv, float scale, int m0, int n0) {
  int t = threadIdx.x, w = t >> 6, l = t & 63;
  int quad = l >> 4, l15 = l & 15;
  int wm_ = w >> 1, wn_ = w & 1;
  int csrc = ((l & 7) ^ (l >> 3)) * 8;   // swizzle folded into per-lane global column
  int rln = l >> 3;

  f32x4 acc[4][4] = {};
  for (int kk = 0; kk < E_DIM; kk += 64) {
    __syncthreads();
#pragma unroll
    for (int i = 0; i < 4; ++i) {        // A: 128 rows, B: 128 rows
      int r0 = i * 32 + w * 8;
      gl2lds16(&A[(size_t)(m0 + r0 + rln) * E_DIM + kk + csrc], &lA[r0 * 64]);
      gl2lds16(&WT[(size_t)(n0 + r0 + rln) * E_DIM + kk + csrc], &lB[r0 * 64]);
    }
    __syncthreads();
#pragma unroll
    for (int ks = 0; ks < 2; ++ks) {
      bf16x8 af[4], bf[4];
#pragma unroll
      for (int mt = 0; mt < 4; ++mt)
        af[mt] = *(const bf16x8*)&lA[swz(wm_ * 64 + mt * 16 + l15, ks * 32 + quad * 8)];
#pragma unroll
      for (int nt = 0; nt < 4; ++nt)
        bf[nt] = *(const bf16x8*)&lB[swz(wn_ * 64 + nt * 16 + l15, ks * 32 + quad * 8)];
#pragma unroll
      for (int mt = 0; mt < 4; ++mt)
#pragma unroll
        for (int nt = 0; nt < 4; ++nt)
          acc[mt][nt] = __builtin_amdgcn_mfma_f32_16x16x32_bf16(af[mt], bf[nt], acc[mt][nt], 0, 0, 0);
    }
  }

#pragma unroll
  for (int nt = 0; nt < 4; ++nt) {
    int col = n0 + wn_ * 64 + nt * 16 + l15;
    float bv = bias[col];
    if constexpr (MODE == 2) {
      int h = col >> 6, d = col & 63;
#pragma unroll
      for (int mt = 0; mt < 4; ++mt) {
        int row = m0 + wm_ * 64 + mt * 16 + quad * 4;   // 4 consecutive k (r=0..3)
        int b = row >> 11, k = row & 2047;
        union { ushort_t u[4]; uint2 v; } pk;
#pragma unroll
        for (int r = 0; r < 4; ++r) pk.u[r] = f2b(acc[mt][nt][r] + bv);
        *(uint2*)&((ushort_t*)Cv)[((((size_t)(b * HEADS + h)) * HD + d) << 11) + k] = pk.v;
      }
    } else {
#pragma unroll
      for (int mt = 0; mt < 4; ++mt) {
#pragma unroll
        for (int r = 0; r < 4; ++r) {
          int rowm = m0 + wm_ * 64 + mt * 16 + quad * 4 + r;   // C/D: col=l&15, row=quad*4+r
          float val = (acc[mt][nt][r] + bv) * scale;
          if constexpr (MODE == 0)
            ((ushort_t*)Cv)[rowm * E_DIM + col] = f2b(val);
          else
            ((float*)Cv)[rowm * E_DIM + col] = val;
        }
      }
    }
  }
}

__launch_bounds__(256)
__global__ void gemm128_bf16(const ushort_t* __restrict__ A, const ushort_t* __restrict__ WT,
                             const float* __restrict__ bias, ushort_t* __restrict__ C, float scale) {
  __shared__ ushort_t lA[128 * 64];
  __shared__ ushort_t lB[128 * 64];
  gemm_core128<0>(lA, lB, A, WT, bias, C, scale, blockIdx.x * 128, blockIdx.y * 128);
}

__launch_bounds__(256)
__global__ void gemm128_f32(const ushort_t* __restrict__ A, const ushort_t* __restrict__ WT,
                            const float* __restrict__ bias, float* __restrict__ C) {
  __shared__ ushort_t lA[128 * 64];
  __shared__ ushort_t lB[128 * 64];
  gemm_core128<1>(lA, lB, A, WT, bias, C, 1.f, blockIdx.x * 128, blockIdx.y * 128);
}

// z=0: qp = (qn@WTq+bq)*QSCALE (row-major)   z=1: Vt = transpose-epilogue(kvn@WTv+bv)
__launch_bounds__(256)
__global__ void proj2_kernel(const ushort_t* __restrict__ qn, const ushort_t* __restrict__ WTq,
                             const float* __restrict__ bq, ushort_t* __restrict__ qp,
                             const ushort_t* __restrict__ kvn, const ushort_t* __restrict__ WTv,
                             const float* __restrict__ bv, ushort_t* __restrict__ Vt) {
  __shared__ ushort_t lA[128 * 64];
  __shared__ ushort_t lB[128 * 64];
  int m0 = blockIdx.x * 128, n0 = blockIdx.y * 128;
  if (blockIdx.z == 0) gemm_core128<0>(lA, lB, qn, WTq, bq, qp, QSCALE, m0, n0);
  else                 gemm_core128<2>(lA, lB, kvn, WTv, bv, Vt, 1.f, m0, n0);
}

// ---------------- flash attention: 32x32x16 MFMA, transposed-S, no-max softmax -------------
// q-tile 128, 4 waves; wave w owns q in [32w,32w+32): lane q=l&31, half=l>>5.
// S^T = K*Q^T per 32-k subtile: C col=lane&31 (=q), row=(r&3)+8*(r>>2)+4*half (=k_local).
// Pipelined single-barrier loop: K/V double-buffered in LDS; tile kt+1's DMA is issued
// BEFORE computing tile kt, drained by the one end-of-iteration __syncthreads (vmcnt(0)).
// P never touches LDS: S^T lanes l/l+32 hold complementary k-quads of the same q-row, so
// v_cvt_pk_bf16_f32 (pack pv pairs) + v_permlane32_swap_b32 (cross-half exchange) builds
// the PV B-fragments in registers (T12). For fragment ksp: pair (g=2(ksp&1), g+1) of
// packed words -> one swap gives word0 (both halves) and word2 (both halves).
// No-max softmax in log2 domain (|s|<=~15), mask -> NEGF before exp2 (exact 0).
__launch_bounds__(256)
__global__ void attn_kernel(const ushort_t* __restrict__ Qp, const ushort_t* __restrict__ Kp,
                            const ushort_t* __restrict__ Vt,
                            const unsigned long long* __restrict__ bits,
                            ushort_t* __restrict__ ctx) {
  __shared__ ushort_t sQ[128 * 64];
  __shared__ ushort_t sK[2][64 * 64];
  __shared__ ushort_t sV[2][64 * 64];   // [d][k]
  int t = threadIdx.x, w = t >> 6, l = t & 63;
  int l31 = l & 31, half = l >> 5;
  int q0 = blockIdx.x * 128;
  int h = blockIdx.y;
  int b = blockIdx.z;
  int bh = b * HEADS + h;
  int myq = w * 32 + l31;
  int csrc = ((l & 7) ^ (l >> 3)) * 8;
  int rln = l >> 3;

  // prologue: stage Q (128 rows) + K/V tile 0 into buffer 0
#pragma unroll
  for (int it = 0; it < 4; ++it) {
    int r0 = it * 32 + w * 8;
    gl2lds16(&Qp[(size_t)(b * SEQ + q0 + r0 + rln) * E_DIM + h * HD + csrc], &sQ[r0 * 64]);
  }
#pragma unroll
  for (int it = 0; it < 2; ++it) {
    int r0 = it * 32 + w * 8;
    gl2lds16(&Kp[(size_t)(b * SEQ + r0 + rln) * E_DIM + h * HD + csrc], &sK[0][r0 * 64]);
    gl2lds16(&Vt[((size_t)bh * HD + r0 + rln) * SEQ + csrc], &sV[0][r0 * 64]);
  }
  __syncthreads();   // drain all prologue DMA

  // Q B-fragments are loop-invariant: B[d][q], d-chunk = ds*16+8*half
  bf16x8 qf[4];
#pragma unroll
  for (int ds = 0; ds < 4; ++ds)
    qf[ds] = *(const bf16x8*)&sQ[swz(myq, ds * 16 + 8 * half)];

  const unsigned long long* mrow = bits + ((size_t)(b * SEQ + q0 + myq) << 5);
  float ls0 = 0.f, ls1 = 0.f, ls2 = 0.f, ls3 = 0.f;   // 4 chains (break serial adds)
  f32x16 o0 = {}, o1 = {};
  int cur = 0;

  for (int kt = 0; kt < 32; ++kt) {
    // mask load FIRST so its vmcnt-wait doesn't drain the staging DMAs behind it
    unsigned long long wmask = mrow[kt];

    if (kt < 31) {            // issue next tile's DMA; overlaps with this tile's compute
      int k0 = (kt + 1) * 64;
      int nxt = cur ^ 1;
#pragma unroll
      for (int it = 0; it < 2; ++it) {
        int r0 = it * 32 + w * 8;
        gl2lds16(&Kp[(size_t)(b * SEQ + k0 + r0 + rln) * E_DIM + h * HD + csrc], &sK[nxt][r0 * 64]);
        gl2lds16(&Vt[((size_t)bh * HD + r0 + rln) * SEQ + k0 + csrc], &sV[nxt][r0 * 64]);
      }
    }

    // S^T: two 32x32 subtiles (kt2 = k-half), 4 d-steps each
    f32x16 s0 = {}, s1 = {};
    __builtin_amdgcn_s_setprio(1);
#pragma unroll
    for (int ds = 0; ds < 4; ++ds) {
      bf16x8 kf0 = *(const bf16x8*)&sK[cur][swz(l31, ds * 16 + 8 * half)];
      bf16x8 kf1 = *(const bf16x8*)&sK[cur][swz(32 + l31, ds * 16 + 8 * half)];
      s0 = __builtin_amdgcn_mfma_f32_32x32x16_bf16(kf0, qf[ds], s0, 0, 0, 0);
      s1 = __builtin_amdgcn_mfma_f32_32x32x16_bf16(kf1, qf[ds], s1, 0, 0, 0);
    }
    __builtin_amdgcn_s_setprio(0);

    // softmax + in-register P->B-fragment build (no LDS)
    bf16x8 pf[4];
#pragma unroll
    for (int kt2 = 0; kt2 < 2; ++kt2) {
      const f32x16& sv = kt2 ? s1 : s0;
      unsigned h32 = ((unsigned)(wmask >> (32 * kt2))) >> (4 * half);
      unsigned wa[4], wb[4];
#pragma unroll
      for (int g = 0; g < 4; ++g) {
        unsigned gb = h32 >> (8 * g);
        float p0 = exp2f((gb & 1u)        ? sv[g * 4 + 0] : NEGF);  // masked -> exactly 0
        float p1 = exp2f(((gb >> 1) & 1u) ? sv[g * 4 + 1] : NEGF);
        float p2 = exp2f(((gb >> 2) & 1u) ? sv[g * 4 + 2] : NEGF);
        float p3 = exp2f(((gb >> 3) & 1u) ? sv[g * 4 + 3] : NEGF);
        ls0 += p0; ls1 += p1; ls2 += p2; ls3 += p3;
        wa[g] = cvt_pk_bf16(p0, p1);   // pv at k' = 8g+4*half+{0,1}
        wb[g] = cvt_pk_bf16(p2, p3);   // pv at k' = 8g+4*half+{2,3}
      }
      // cross-half exchange: (wa[0],wa[1]) -> word0/word2 of frag 2*kt2,
      //                      (wa[2],wa[3]) -> word0/word2 of frag 2*kt2+1 (wb: word1/word3)
      asm("v_permlane32_swap_b32 %0, %1" : "+v"(wa[0]), "+v"(wa[1]));
      asm("v_permlane32_swap_b32 %0, %1" : "+v"(wb[0]), "+v"(wb[1]));
      asm("v_permlane32_swap_b32 %0, %1" : "+v"(wa[2]), "+v"(wa[3]));
      asm("v_permlane32_swap_b32 %0, %1" : "+v"(wb[2]), "+v"(wb[3]));
      union { unsigned u[4]; bf16x8 v; } f0, f1;
      f0.u[0] = wa[0]; f0.u[1] = wb[0]; f0.u[2] = wa[1]; f0.u[3] = wb[1];
      f1.u[0] = wa[2]; f1.u[1] = wb[2]; f1.u[2] = wa[3]; f1.u[3] = wb[3];
      pf[kt2 * 2 + 0] = f0.v;
      pf[kt2 * 2 + 1] = f1.v;
    }

    // O^T += V^T P^T  (P fragments in registers)
    __builtin_amdgcn_s_setprio(1);
#pragma unroll
    for (int ksp = 0; ksp < 4; ++ksp) {
      bf16x8 vf0 = *(const bf16x8*)&sV[cur][swz(l31, ksp * 16 + 8 * half)];
      bf16x8 vf1 = *(const bf16x8*)&sV[cur][swz(32 + l31, ksp * 16 + 8 * half)];
      o0 = __builtin_amdgcn_mfma_f32_32x32x16_bf16(vf0, pf[ksp], o0, 0, 0, 0);
      o1 = __builtin_amdgcn_mfma_f32_32x32x16_bf16(vf1, pf[ksp], o1, 0, 0, 0);
    }
    __builtin_amdgcn_s_setprio(0);

    __syncthreads();   // drains next-tile DMA (vmcnt 0) + protects buf reuse
    cur ^= 1;
  }

  // lanes l and l+32 share q -> one shuffle completes the row sum
  float lsum = (ls0 + ls1) + (ls2 + ls3);
  lsum += __shfl_xor(lsum, 32);
  float inv = (lsum > 0.f) ? 1.f / lsum : 0.f;   // all-masked row -> 0 (nan_to_num)
  size_t base = (size_t)(b * SEQ + q0 + myq) * E_DIM + h * HD;
#pragma unroll
  for (int dt = 0; dt < 2; ++dt) {
    const f32x16& oo = dt ? o1 : o0;
#pragma unroll
    for (int g = 0; g < 4; ++g) {
      union { ushort_t u[4]; uint2 v; } ov;
#pragma unroll
      for (int r = 0; r < 4; ++r) ov.u[r] = f2b(oo[g * 4 + r] * inv);
      *(uint2*)&ctx[base + dt * 32 + g * 8 + 4 * half] = ov.v;   // d=(r)+8g+4*half+32dt
    }
  }
}

// ---------------- launch ----------------
// fp32 in/out, bf16 internals. ws = 20 MiB: bufA(8) bufB(8) WT(2) bits(2).
// d_out (16 MB fp32) = two 8 MB bf16 slots dlo/dhi. 5 dispatches:
//   1 prep:  WT, bits, qn->dlo, kvn->bufA
//   2 proj2: z0 qp=(qn@WTq+bq)*QSCALE -> dhi ; z1 Vt=T(kvn@WTv+bv) -> bufB  (disjoint io)
//   3 kp:    kvn@WTk+bk -> dlo          [qn dead]
//   4 attn:  (dhi,dlo,bufB,bits) -> bufA  [kvn dead]
//   5 out:   bufA@WTo+bo -> d_out fp32    [qp/kp/Vt dead]
extern "C" void kernel_launch(void* const* d_in, const int* in_sizes, int n_in,
                              void* d_out, int out_size, void* d_ws, size_t ws_size,
                              hipStream_t stream) {
  const float* query     = (const float*)d_in[0];
  const float* key_value = (const float*)d_in[1];
  const int*   kv_mask   = (const int*)d_in[2];
  const int*   sp_mask   = (const int*)d_in[3];
  const float* ln_q_g  = (const float*)d_in[4];
  const float* ln_q_b  = (const float*)d_in[5];
  const float* ln_kv_g = (const float*)d_in[6];
  const float* ln_kv_b = (const float*)d_in[7];
  const float* Wq = (const float*)d_in[8];
  const float* bq = (const float*)d_in[9];
  const float* Wk = (const float*)d_in[10];
  const float* bk = (const float*)d_in[11];
  const float* Wv = (const float*)d_in[12];
  const float* bv = (const float*)d_in[13];
  const float* Wo = (const float*)d_in[14];
  const float* bo = (const float*)d_in[15];

  const size_t NB = (size_t)NROWS * E_DIM;       // 8 MiB bf16 slot
  char* ws = (char*)d_ws;
  ushort_t* bufA = (ushort_t*)ws;                // kvn -> ctx
  ushort_t* bufB = bufA + NB;                    // Vt
  ushort_t* WT   = bufB + NB;                    // 4 x 512x512 bf16 = 2 MiB
  ushort_t* WTq = WT;
  ushort_t* WTk = WTq + E_DIM * E_DIM;
  ushort_t* WTv = WTk + E_DIM * E_DIM;
  ushort_t* WTo = WTv + E_DIM * E_DIM;
  unsigned long long* bits = (unsigned long long*)(WTo + E_DIM * E_DIM);  // 2 MiB

  ushort_t* dlo = (ushort_t*)d_out;              // qn, then kp
  ushort_t* dhi = dlo + NB;                      // qp

  prep_kernel<<<7168, 256, 0, stream>>>(Wq, Wk, Wv, Wo, WT, kv_mask, sp_mask, bits,
                                        query, key_value, ln_q_g, ln_q_b, ln_kv_g, ln_kv_b,
                                        dlo, bufA);

  proj2_kernel<<<dim3(64, 4, 2), 256, 0, stream>>>(dlo, WTq, bq, dhi,
                                                   bufA, WTv, bv, bufB);

  gemm128_bf16<<<dim3(64, 4), 256, 0, stream>>>(bufA, WTk, bk, dlo, 1.f);   // kp

  attn_kernel<<<dim3(16, HEADS, 4), 256, 0, stream>>>(dhi, dlo, bufB, bits, bufA);

  gemm128_f32<<<dim3(64, 4), 256, 0, stream>>>(bufA, WTo, bo, (float*)d_out);
}

// Round 2
// 269.571 us; speedup vs baseline: 1.0661x; 1.0661x over previous
//
#include <hip/hip_runtime.h>
#include <hip/hip_bf16.h>
#include <math.h>

typedef unsigned short ushort_t;
typedef __attribute__((ext_vector_type(8))) __bf16 bf16x8;
typedef __attribute__((ext_vector_type(4))) float f32x4;
typedef __attribute__((ext_vector_type(16))) float f32x16;
typedef __attribute__((ext_vector_type(4))) unsigned int u32x4;

#define E_DIM 512
#define HEADS 8
#define HD 64
#define SEQ 2048
#define NROWS 8192        // B * SEQ
#define NEGF (-1e30f)
#define QSCALE 0.18033688011112042f   // 0.125 * log2(e): scores in log2 domain

static __device__ __forceinline__ unsigned short f2b(float f) {
  unsigned int x;
  __builtin_memcpy(&x, &f, 4);
  x += 0x7fffu + ((x >> 16) & 1u);   // RNE (cold epilogues only)
  return (unsigned short)(x >> 16);
}

// v_cvt_pk_bf16_f32: pack 2 f32 -> 2 bf16 (RNE) in one u32. No builtin on gfx950.
static __device__ __forceinline__ unsigned cvt_pk_bf16(float lo, float hi) {
  unsigned r;
  asm("v_cvt_pk_bf16_f32 %0, %1, %2" : "=v"(r) : "v"(lo), "v"(hi));
  return r;
}

// raw v_exp_f32 (2^x): skips ocml's subnormal-fixup sequence. -1e30 -> exactly 0.
static __device__ __forceinline__ float fexp2(float x) {
  float r;
  asm("v_exp_f32 %0, %1" : "=v"(r) : "v"(x));
  return r;
}

// XOR-swizzled LDS index for 64-col bf16 tiles (16B chunks) — conflict-free reads.
static __device__ __forceinline__ int swz(int row, int col) {
  return row * 64 + ((((col >> 3) ^ (row & 7)) & 7) << 3) + (col & 7);
}

// Async 16B/lane global->LDS DMA; dest = lds_base + lane*16B (wave-uniform base).
// Caller realizes the swizzle by permuting the per-lane GLOBAL address.
static __device__ __forceinline__ void gl2lds16(const ushort_t* g, ushort_t* s) {
#if __has_builtin(__builtin_amdgcn_global_load_lds)
  __builtin_amdgcn_global_load_lds(
      (const __attribute__((address_space(1))) unsigned int*)(uintptr_t)g,
      (__attribute__((address_space(3))) unsigned int*)(uintptr_t)s,
      16, 0, 0);
#else
  int l = threadIdx.x & 63;
  *(u32x4*)(s + l * 8) = *(const u32x4*)g;
#endif
}

// ---------------- prep: fused transposeW(x4) + pack_mask + 2x LayerNorm ----------------
__launch_bounds__(256)
__global__ void prep_kernel(const float* __restrict__ Wq, const float* __restrict__ Wk,
                            const float* __restrict__ Wv, const float* __restrict__ Wo,
                            ushort_t* __restrict__ WT,
                            const int* __restrict__ kvm, const int* __restrict__ sp,
                            unsigned long long* __restrict__ bits,
                            const float* __restrict__ xq, const float* __restrict__ xkv,
                            const float* __restrict__ gq, const float* __restrict__ bq,
                            const float* __restrict__ gkv, const float* __restrict__ bkv,
                            ushort_t* __restrict__ yq, ushort_t* __restrict__ ykv) {
  int blk = blockIdx.x;
  int t = threadIdx.x;
  if (blk < 1024) {                       // ---- weight transpose+cast
    int z = blk >> 8, rem = blk & 255;
    const float* in = (z == 0) ? Wq : (z == 1) ? Wk : (z == 2) ? Wv : Wo;
    ushort_t* o = WT + (size_t)z * E_DIM * E_DIM;
    __shared__ float tile[32 * 33];
    int tx = t & 31, ty = t >> 5;
    int n0 = (rem & 15) * 32, k0 = (rem >> 4) * 32;
#pragma unroll
    for (int i = 0; i < 4; ++i) {
      int k = ty + i * 8;
      tile[k * 33 + tx] = in[(k0 + k) * E_DIM + n0 + tx];
    }
    __syncthreads();
#pragma unroll
    for (int i = 0; i < 4; ++i) {
      int n = ty + i * 8;
      o[(n0 + n) * E_DIM + k0 + tx] = f2b(tile[tx * 33 + n]);
    }
  } else if (blk < 3072) {                // ---- mask pack (ballot, coalesced)
    int w = t >> 6, l = t & 63;
    int row = (blk - 1024) * 4 + w;
    int b = row >> 11;
    const int* sprow = sp + ((size_t)row << 11);
    const int* kvrow = kvm + (b << 11);
    unsigned long long* out = bits + ((size_t)row << 5);
#pragma unroll 4
    for (int it = 0; it < 32; ++it) {
      int k = it * 64 + l;
      unsigned long long m = __ballot(sprow[k] != 0 && kvrow[k] != 0);
      if (l == 0) out[it] = m;
    }
  } else {                                // ---- LayerNorm, both tensors
    int idx = blk - 3072;
    int which = idx >> 11;
    const float* x = which ? xkv : xq;
    const float* g = which ? gkv : gq;
    const float* bb = which ? bkv : bq;
    ushort_t* y = which ? ykv : yq;
    int w = t >> 6, l = t & 63;
    int row = (idx & 2047) * 4 + w;
    f32x4 x0 = *(const f32x4*)&x[row * E_DIM + l * 8];
    f32x4 x1 = *(const f32x4*)&x[row * E_DIM + l * 8 + 4];
    float xf[8], s = 0.f, ss = 0.f;
#pragma unroll
    for (int j = 0; j < 8; ++j) {
      xf[j] = (j < 4) ? x0[j] : x1[j - 4];
      s += xf[j];
      ss += xf[j] * xf[j];
    }
#pragma unroll
    for (int off = 32; off > 0; off >>= 1) {
      s += __shfl_xor(s, off);
      ss += __shfl_xor(ss, off);
    }
    float mu = s * (1.f / 512.f);
    float var = fmaxf(ss * (1.f / 512.f) - mu * mu, 0.f);
    float rs = rsqrtf(var + 1e-5f);
    f32x4 g0 = *(const f32x4*)&g[l * 8];
    f32x4 g1 = *(const f32x4*)&g[l * 8 + 4];
    f32x4 b0 = *(const f32x4*)&bb[l * 8];
    f32x4 b1 = *(const f32x4*)&bb[l * 8 + 4];
#pragma unroll
    for (int j = 0; j < 8; ++j) {
      float gv = (j < 4) ? g0[j] : g1[j - 4];
      float bv = (j < 4) ? b0[j] : b1[j - 4];
      y[row * E_DIM + l * 8 + j] = f2b((xf[j] - mu) * rs * gv + bv);
    }
  }
}

// ---------------- GEMM core, 128x128 tile, BK=64, 4 waves in 2x2 (each 64x64) --------------
// MODE 0: bf16 row-major C (with scale)  MODE 1: fp32 row-major C
// MODE 2: bf16 Vt-transposed epilogue  Vt[((b*8+h)*64+d)*2048 + k]  (packed uint2 along k)
template <int MODE>
static __device__ __forceinline__ void gemm_core128(ushort_t* lA, ushort_t* lB,
                                                    const ushort_t* __restrict__ A,
                                                    const ushort_t* __restrict__ WT,
                                                    const float* __restrict__ bias,
                                                    void* Cv, float scale, int m0, int n0) {
  int t = threadIdx.x, w = t >> 6, l = t & 63;
  int quad = l >> 4, l15 = l & 15;
  int wm_ = w >> 1, wn_ = w & 1;
  int csrc = ((l & 7) ^ (l >> 3)) * 8;   // swizzle folded into per-lane global column
  int rln = l >> 3;

  f32x4 acc[4][4] = {};
  for (int kk = 0; kk < E_DIM; kk += 64) {
    __syncthreads();
#pragma unroll
    for (int i = 0; i < 4; ++i) {        // A: 128 rows, B: 128 rows
      int r0 = i * 32 + w * 8;
      gl2lds16(&A[(size_t)(m0 + r0 + rln) * E_DIM + kk + csrc], &lA[r0 * 64]);
      gl2lds16(&WT[(size_t)(n0 + r0 + rln) * E_DIM + kk + csrc], &lB[r0 * 64]);
    }
    __syncthreads();
#pragma unroll
    for (int ks = 0; ks < 2; ++ks) {
      bf16x8 af[4], bf[4];
#pragma unroll
      for (int mt = 0; mt < 4; ++mt)
        af[mt] = *(const bf16x8*)&lA[swz(wm_ * 64 + mt * 16 + l15, ks * 32 + quad * 8)];
#pragma unroll
      for (int nt = 0; nt < 4; ++nt)
        bf[nt] = *(const bf16x8*)&lB[swz(wn_ * 64 + nt * 16 + l15, ks * 32 + quad * 8)];
#pragma unroll
      for (int mt = 0; mt < 4; ++mt)
#pragma unroll
        for (int nt = 0; nt < 4; ++nt)
          acc[mt][nt] = __builtin_amdgcn_mfma_f32_16x16x32_bf16(af[mt], bf[nt], acc[mt][nt], 0, 0, 0);
    }
  }

#pragma unroll
  for (int nt = 0; nt < 4; ++nt) {
    int col = n0 + wn_ * 64 + nt * 16 + l15;
    float bv = bias[col];
    if constexpr (MODE == 2) {
      int h = col >> 6, d = col & 63;
#pragma unroll
      for (int mt = 0; mt < 4; ++mt) {
        int row = m0 + wm_ * 64 + mt * 16 + quad * 4;   // 4 consecutive k (r=0..3)
        int b = row >> 11, k = row & 2047;
        union { ushort_t u[4]; uint2 v; } pk;
#pragma unroll
        for (int r = 0; r < 4; ++r) pk.u[r] = f2b(acc[mt][nt][r] + bv);
        *(uint2*)&((ushort_t*)Cv)[((((size_t)(b * HEADS + h)) * HD + d) << 11) + k] = pk.v;
      }
    } else {
#pragma unroll
      for (int mt = 0; mt < 4; ++mt) {
#pragma unroll
        for (int r = 0; r < 4; ++r) {
          int rowm = m0 + wm_ * 64 + mt * 16 + quad * 4 + r;   // C/D: col=l&15, row=quad*4+r
          float val = (acc[mt][nt][r] + bv) * scale;
          if constexpr (MODE == 0)
            ((ushort_t*)Cv)[rowm * E_DIM + col] = f2b(val);
          else
            ((float*)Cv)[rowm * E_DIM + col] = val;
        }
      }
    }
  }
}

__launch_bounds__(256)
__global__ void gemm128_bf16(const ushort_t* __restrict__ A, const ushort_t* __restrict__ WT,
                             const float* __restrict__ bias, ushort_t* __restrict__ C, float scale) {
  __shared__ ushort_t lA[128 * 64];
  __shared__ ushort_t lB[128 * 64];
  gemm_core128<0>(lA, lB, A, WT, bias, C, scale, blockIdx.x * 128, blockIdx.y * 128);
}

__launch_bounds__(256)
__global__ void gemm128_f32(const ushort_t* __restrict__ A, const ushort_t* __restrict__ WT,
                            const float* __restrict__ bias, float* __restrict__ C) {
  __shared__ ushort_t lA[128 * 64];
  __shared__ ushort_t lB[128 * 64];
  gemm_core128<1>(lA, lB, A, WT, bias, C, 1.f, blockIdx.x * 128, blockIdx.y * 128);
}

// z=0: qp = (qn@WTq+bq)*QSCALE (row-major)   z=1: Vt = transpose-epilogue(kvn@WTv+bv)
__launch_bounds__(256)
__global__ void proj2_kernel(const ushort_t* __restrict__ qn, const ushort_t* __restrict__ WTq,
                             const float* __restrict__ bq, ushort_t* __restrict__ qp,
                             const ushort_t* __restrict__ kvn, const ushort_t* __restrict__ WTv,
                             const float* __restrict__ bv, ushort_t* __restrict__ Vt) {
  __shared__ ushort_t lA[128 * 64];
  __shared__ ushort_t lB[128 * 64];
  int m0 = blockIdx.x * 128, n0 = blockIdx.y * 128;
  if (blockIdx.z == 0) gemm_core128<0>(lA, lB, qn, WTq, bq, qp, QSCALE, m0, n0);
  else                 gemm_core128<2>(lA, lB, kvn, WTv, bv, Vt, 1.f, m0, n0);
}

// ---------------- flash attention: 32x32x16 MFMA, transposed-S, no-max softmax -------------
// OCCUPANCY BUILD: q-tile 64, block = 4 waves = (2 q-waves) x (2 k-slices).
// Wave (qw,ks): q rows [32qw,32qw+32), k-tiles kt = 2*t+ks (16 tiles). Partial O/lsum are
// ADDITIVE (no-max log2 softmax) -> cross-slice merge via LDS at the end.
// LDS = 40KB (sQ 8K + per-slice single-buffered K/V 4x8K) -> 4 blocks/CU = 16 waves/CU,
// 2x the old occupancy (old: 512 blocks = 2/CU grid-limited at 48KB LDS).
// XCD-bijective swizzle: flat -> work=(flat&7)*128+(flat>>3): each (b,h) K/V panel lives
// entirely on ONE XCD L2 (kills the ~2.7x HBM overfetch from round-robin q-tiles).
// S^T = K*Q^T: C col=lane&31 (=q), row=(r&3)+8*(r>>2)+4*half (=k_local). P stays in
// registers via cvt_pk_bf16 + permlane32_swap (T12). Masked scores -> NEGF -> exp2 = 0.
__launch_bounds__(256)
__global__ void attn_kernel(const ushort_t* __restrict__ Qp, const ushort_t* __restrict__ Kp,
                            const ushort_t* __restrict__ Vt,
                            const unsigned long long* __restrict__ bits,
                            ushort_t* __restrict__ ctx) {
  __shared__ __align__(16) char smemb[40960];
  ushort_t* sQ = (ushort_t*)smemb;                       // [0, 8192)
  int t = threadIdx.x, w = t >> 6, l = t & 63;
  int qw = w & 1, ks = w >> 1;
  ushort_t* sK = (ushort_t*)(smemb + 8192 + ks * 8192);  // [8192, 24576)
  ushort_t* sV = (ushort_t*)(smemb + 24576 + ks * 8192); // [24576, 40960)
  int l31 = l & 31, half = l >> 5;

  int flat = blockIdx.x;
  int work = (flat & 7) * 128 + (flat >> 3);   // bijective XCD chunking (1024 = 8*128)
  int qblk = work & 31;
  int h = (work >> 5) & 7;
  int b = work >> 8;
  int q0 = qblk * 64;
  int bh = b * HEADS + h;
  int myq = qw * 32 + l31;
  int csrc = ((l & 7) ^ (l >> 3)) * 8;
  int rln = l >> 3;

  // stage Q (64 rows, all 4 waves), drained by tile 0's second barrier
#pragma unroll
  for (int it = 0; it < 2; ++it) {
    int r0 = w * 16 + it * 8;
    gl2lds16(&Qp[(size_t)(b * SEQ + q0 + r0 + rln) * E_DIM + h * HD + csrc], &sQ[r0 * 64]);
  }

  const unsigned long long* mrow = bits + ((size_t)(b * SEQ + q0 + myq) << 5);
  float ls0 = 0.f, ls1 = 0.f, ls2 = 0.f, ls3 = 0.f;
  f32x16 o0 = {}, o1 = {};
  bf16x8 qf[4];

  for (int t16 = 0; t16 < 16; ++t16) {
    int kt = t16 * 2 + ks;
    int k0 = kt * 64;
    unsigned long long wmask = mrow[kt];
    __syncthreads();   // prev tile's sK/sV reads done (both slices)
    // slice waves (2 per slice) stage this slice's K/V tile: 8 row-groups each of K and V
#pragma unroll
    for (int it = 0; it < 4; ++it) {
      int r0 = (it * 2 + qw) * 8;
      gl2lds16(&Kp[(size_t)(b * SEQ + k0 + r0 + rln) * E_DIM + h * HD + csrc], &sK[r0 * 64]);
      gl2lds16(&Vt[((size_t)bh * HD + r0 + rln) * SEQ + k0 + csrc], &sV[r0 * 64]);
    }
    __syncthreads();   // DMA drained (each wave waits its own vmcnt(0) then barrier)
    if (t16 == 0) {    // cache Q B-fragments: B[d][q]=Q[q][d], d-chunk = ds*16+8*half
#pragma unroll
      for (int ds = 0; ds < 4; ++ds)
        qf[ds] = *(const bf16x8*)&sQ[swz(myq, ds * 16 + 8 * half)];
    }

    // S^T: two 32x32 subtiles (kt2 = k-half), 4 d-steps each
    f32x16 s0 = {}, s1 = {};
    __builtin_amdgcn_s_setprio(1);
#pragma unroll
    for (int ds = 0; ds < 4; ++ds) {
      bf16x8 kf0 = *(const bf16x8*)&sK[swz(l31, ds * 16 + 8 * half)];
      bf16x8 kf1 = *(const bf16x8*)&sK[swz(32 + l31, ds * 16 + 8 * half)];
      s0 = __builtin_amdgcn_mfma_f32_32x32x16_bf16(kf0, qf[ds], s0, 0, 0, 0);
      s1 = __builtin_amdgcn_mfma_f32_32x32x16_bf16(kf1, qf[ds], s1, 0, 0, 0);
    }
    __builtin_amdgcn_s_setprio(0);

    // softmax + in-register P->B-fragment build (no LDS)
    bf16x8 pf[4];
#pragma unroll
    for (int kt2 = 0; kt2 < 2; ++kt2) {
      const f32x16& sv = kt2 ? s1 : s0;
      unsigned h32 = ((unsigned)(wmask >> (32 * kt2))) >> (4 * half);
      unsigned wa[4], wb[4];
#pragma unroll
      for (int g = 0; g < 4; ++g) {
        unsigned gb = h32 >> (8 * g);
        float p0 = fexp2((gb & 1u)        ? sv[g * 4 + 0] : NEGF);  // masked -> exactly 0
        float p1 = fexp2(((gb >> 1) & 1u) ? sv[g * 4 + 1] : NEGF);
        float p2 = fexp2(((gb >> 2) & 1u) ? sv[g * 4 + 2] : NEGF);
        float p3 = fexp2(((gb >> 3) & 1u) ? sv[g * 4 + 3] : NEGF);
        ls0 += p0; ls1 += p1; ls2 += p2; ls3 += p3;
        wa[g] = cvt_pk_bf16(p0, p1);   // pv at k' = 8g+4*half+{0,1}
        wb[g] = cvt_pk_bf16(p2, p3);   // pv at k' = 8g+4*half+{2,3}
      }
      asm("v_permlane32_swap_b32 %0, %1" : "+v"(wa[0]), "+v"(wa[1]));
      asm("v_permlane32_swap_b32 %0, %1" : "+v"(wb[0]), "+v"(wb[1]));
      asm("v_permlane32_swap_b32 %0, %1" : "+v"(wa[2]), "+v"(wa[3]));
      asm("v_permlane32_swap_b32 %0, %1" : "+v"(wb[2]), "+v"(wb[3]));
      union { unsigned u[4]; bf16x8 v; } f0, f1;
      f0.u[0] = wa[0]; f0.u[1] = wb[0]; f0.u[2] = wa[1]; f0.u[3] = wb[1];
      f1.u[0] = wa[2]; f1.u[1] = wb[2]; f1.u[2] = wa[3]; f1.u[3] = wb[3];
      pf[kt2 * 2 + 0] = f0.v;
      pf[kt2 * 2 + 1] = f1.v;
    }

    // O^T += V^T P^T  (P fragments in registers)
    __builtin_amdgcn_s_setprio(1);
#pragma unroll
    for (int ksp = 0; ksp < 4; ++ksp) {
      bf16x8 vf0 = *(const bf16x8*)&sV[swz(l31, ksp * 16 + 8 * half)];
      bf16x8 vf1 = *(const bf16x8*)&sV[swz(32 + l31, ksp * 16 + 8 * half)];
      o0 = __builtin_amdgcn_mfma_f32_32x32x16_bf16(vf0, pf[ksp], o0, 0, 0, 0);
      o1 = __builtin_amdgcn_mfma_f32_32x32x16_bf16(vf1, pf[ksp], o1, 0, 0, 0);
    }
    __builtin_amdgcn_s_setprio(0);
  }

  // within-wave: lanes l and l+32 share q -> one shuffle completes the partial row sum
  float lsum = (ls0 + ls1) + (ls2 + ls3);
  lsum += __shfl_xor(lsum, 32);

  // cross-slice merge: slice 1 writes partials to LDS (K/V area is dead), slice 0 adds.
  __syncthreads();                       // all compute done before overwriting K/V area
  float* mrg = (float*)(smemb + 8192);   // [2 qw][64 lanes][33 floats] = 16.9KB
  if (ks == 1) {
    float* e = mrg + (qw * 64 + l) * 33;
#pragma unroll
    for (int r = 0; r < 16; ++r) e[r] = o0[r];
#pragma unroll
    for (int r = 0; r < 16; ++r) e[16 + r] = o1[r];
    e[32] = lsum;
  }
  __syncthreads();
  if (ks == 0) {
    const float* e = mrg + (qw * 64 + l) * 33;
#pragma unroll
    for (int r = 0; r < 16; ++r) o0[r] += e[r];
#pragma unroll
    for (int r = 0; r < 16; ++r) o1[r] += e[16 + r];
    lsum += e[32];
    float inv = (lsum > 0.f) ? 1.f / lsum : 0.f;   // all-masked row -> 0 (nan_to_num)
    size_t base = (size_t)(b * SEQ + q0 + myq) * E_DIM + h * HD;
#pragma unroll
    for (int dt = 0; dt < 2; ++dt) {
      const f32x16& oo = dt ? o1 : o0;
#pragma unroll
      for (int g = 0; g < 4; ++g) {
        union { ushort_t u[4]; uint2 v; } ov;
#pragma unroll
        for (int r = 0; r < 4; ++r) ov.u[r] = f2b(oo[g * 4 + r] * inv);
        *(uint2*)&ctx[base + dt * 32 + g * 8 + 4 * half] = ov.v;   // d=(r)+8g+4*half+32dt
      }
    }
  }
}

// ---------------- launch ----------------
// fp32 in/out, bf16 internals. ws = 20 MiB: bufA(8) bufB(8) WT(2) bits(2).
// d_out (16 MB fp32) = two 8 MB bf16 slots dlo/dhi. 5 dispatches:
//   1 prep:  WT, bits, qn->dlo, kvn->bufA
//   2 proj2: z0 qp=(qn@WTq+bq)*QSCALE -> dhi ; z1 Vt=T(kvn@WTv+bv) -> bufB  (disjoint io)
//   3 kp:    kvn@WTk+bk -> dlo          [qn dead]
//   4 attn:  (dhi,dlo,bufB,bits) -> bufA  [kvn dead]
//   5 out:   bufA@WTo+bo -> d_out fp32    [qp/kp/Vt dead]
extern "C" void kernel_launch(void* const* d_in, const int* in_sizes, int n_in,
                              void* d_out, int out_size, void* d_ws, size_t ws_size,
                              hipStream_t stream) {
  const float* query     = (const float*)d_in[0];
  const float* key_value = (const float*)d_in[1];
  const int*   kv_mask   = (const int*)d_in[2];
  const int*   sp_mask   = (const int*)d_in[3];
  const float* ln_q_g  = (const float*)d_in[4];
  const float* ln_q_b  = (const float*)d_in[5];
  const float* ln_kv_g = (const float*)d_in[6];
  const float* ln_kv_b = (const float*)d_in[7];
  const float* Wq = (const float*)d_in[8];
  const float* bq = (const float*)d_in[9];
  const float* Wk = (const float*)d_in[10];
  const float* bk = (const float*)d_in[11];
  const float* Wv = (const float*)d_in[12];
  const float* bv = (const float*)d_in[13];
  const float* Wo = (const float*)d_in[14];
  const float* bo = (const float*)d_in[15];

  const size_t NB = (size_t)NROWS * E_DIM;       // 8 MiB bf16 slot
  char* ws = (char*)d_ws;
  ushort_t* bufA = (ushort_t*)ws;                // kvn -> ctx
  ushort_t* bufB = bufA + NB;                    // Vt
  ushort_t* WT   = bufB + NB;                    // 4 x 512x512 bf16 = 2 MiB
  ushort_t* WTq = WT;
  ushort_t* WTk = WTq + E_DIM * E_DIM;
  ushort_t* WTv = WTk + E_DIM * E_DIM;
  ushort_t* WTo = WTv + E_DIM * E_DIM;
  unsigned long long* bits = (unsigned long long*)(WTo + E_DIM * E_DIM);  // 2 MiB

  ushort_t* dlo = (ushort_t*)d_out;              // qn, then kp
  ushort_t* dhi = dlo + NB;                      // qp

  prep_kernel<<<7168, 256, 0, stream>>>(Wq, Wk, Wv, Wo, WT, kv_mask, sp_mask, bits,
                                        query, key_value, ln_q_g, ln_q_b, ln_kv_g, ln_kv_b,
                                        dlo, bufA);

  proj2_kernel<<<dim3(64, 4, 2), 256, 0, stream>>>(dlo, WTq, bq, dhi,
                                                   bufA, WTv, bv, bufB);

  gemm128_bf16<<<dim3(64, 4), 256, 0, stream>>>(bufA, WTk, bk, dlo, 1.f);   // kp

  attn_kernel<<<1024, 256, 0, stream>>>(dhi, dlo, bufB, bits, bufA);

  gemm128_f32<<<dim3(64, 4), 256, 0, stream>>>(bufA, WTo, bo, (float*)d_out);
}

// Round 3
// 259.580 us; speedup vs baseline: 1.1072x; 1.0385x over previous
//
#include <hip/hip_runtime.h>
#include <hip/hip_bf16.h>
#include <math.h>

typedef unsigned short ushort_t;
typedef __attribute__((ext_vector_type(8))) __bf16 bf16x8;
typedef __attribute__((ext_vector_type(4))) float f32x4;
typedef __attribute__((ext_vector_type(16))) float f32x16;
typedef __attribute__((ext_vector_type(4))) unsigned int u32x4;

#define E_DIM 512
#define HEADS 8
#define HD 64
#define SEQ 2048
#define NROWS 8192        // B * SEQ
#define NEGF (-1e30f)
#define QSCALE 0.18033688011112042f   // 0.125 * log2(e): scores in log2 domain

static __device__ __forceinline__ unsigned short f2b(float f) {
  unsigned int x;
  __builtin_memcpy(&x, &f, 4);
  x += 0x7fffu + ((x >> 16) & 1u);   // RNE (cold epilogues only)
  return (unsigned short)(x >> 16);
}

// v_cvt_pk_bf16_f32: pack 2 f32 -> 2 bf16 (RNE) in one u32. No builtin on gfx950.
static __device__ __forceinline__ unsigned cvt_pk_bf16(float lo, float hi) {
  unsigned r;
  asm("v_cvt_pk_bf16_f32 %0, %1, %2" : "=v"(r) : "v"(lo), "v"(hi));
  return r;
}

// raw v_exp_f32 (2^x): skips ocml's subnormal-fixup sequence. -1e30 -> exactly 0.
static __device__ __forceinline__ float fexp2(float x) {
  float r;
  asm("v_exp_f32 %0, %1" : "=v"(r) : "v"(x));
  return r;
}

// XOR-swizzled LDS index for 64-col bf16 tiles (16B chunks) — conflict-free reads.
static __device__ __forceinline__ int swz(int row, int col) {
  return row * 64 + ((((col >> 3) ^ (row & 7)) & 7) << 3) + (col & 7);
}

// Async 16B/lane global->LDS DMA; dest = lds_base + lane*16B (wave-uniform base).
// Caller realizes the swizzle by permuting the per-lane GLOBAL address.
static __device__ __forceinline__ void gl2lds16(const ushort_t* g, ushort_t* s) {
#if __has_builtin(__builtin_amdgcn_global_load_lds)
  __builtin_amdgcn_global_load_lds(
      (const __attribute__((address_space(1))) unsigned int*)(uintptr_t)g,
      (__attribute__((address_space(3))) unsigned int*)(uintptr_t)s,
      16, 0, 0);
#else
  int l = threadIdx.x & 63;
  *(u32x4*)(s + l * 8) = *(const u32x4*)g;
#endif
}

// ---------------- prep: fused transposeW(x4) + pack_mask + 2x LayerNorm ----------------
__launch_bounds__(256)
__global__ void prep_kernel(const float* __restrict__ Wq, const float* __restrict__ Wk,
                            const float* __restrict__ Wv, const float* __restrict__ Wo,
                            ushort_t* __restrict__ WT,
                            const int* __restrict__ kvm, const int* __restrict__ sp,
                            unsigned long long* __restrict__ bits,
                            const float* __restrict__ xq, const float* __restrict__ xkv,
                            const float* __restrict__ gq, const float* __restrict__ bq,
                            const float* __restrict__ gkv, const float* __restrict__ bkv,
                            ushort_t* __restrict__ yq, ushort_t* __restrict__ ykv) {
  int blk = blockIdx.x;
  int t = threadIdx.x;
  if (blk < 1024) {                       // ---- weight transpose+cast
    int z = blk >> 8, rem = blk & 255;
    const float* in = (z == 0) ? Wq : (z == 1) ? Wk : (z == 2) ? Wv : Wo;
    ushort_t* o = WT + (size_t)z * E_DIM * E_DIM;
    __shared__ float tile[32 * 33];
    int tx = t & 31, ty = t >> 5;
    int n0 = (rem & 15) * 32, k0 = (rem >> 4) * 32;
#pragma unroll
    for (int i = 0; i < 4; ++i) {
      int k = ty + i * 8;
      tile[k * 33 + tx] = in[(k0 + k) * E_DIM + n0 + tx];
    }
    __syncthreads();
#pragma unroll
    for (int i = 0; i < 4; ++i) {
      int n = ty + i * 8;
      o[(n0 + n) * E_DIM + k0 + tx] = f2b(tile[tx * 33 + n]);
    }
  } else if (blk < 3072) {                // ---- mask pack (ballot, coalesced)
    int w = t >> 6, l = t & 63;
    int row = (blk - 1024) * 4 + w;
    int b = row >> 11;
    const int* sprow = sp + ((size_t)row << 11);
    const int* kvrow = kvm + (b << 11);
    unsigned long long* out = bits + ((size_t)row << 5);
#pragma unroll 4
    for (int it = 0; it < 32; ++it) {
      int k = it * 64 + l;
      unsigned long long m = __ballot(sprow[k] != 0 && kvrow[k] != 0);
      if (l == 0) out[it] = m;
    }
  } else {                                // ---- LayerNorm, both tensors
    int idx = blk - 3072;
    int which = idx >> 11;
    const float* x = which ? xkv : xq;
    const float* g = which ? gkv : gq;
    const float* bb = which ? bkv : bq;
    ushort_t* y = which ? ykv : yq;
    int w = t >> 6, l = t & 63;
    int row = (idx & 2047) * 4 + w;
    f32x4 x0 = *(const f32x4*)&x[row * E_DIM + l * 8];
    f32x4 x1 = *(const f32x4*)&x[row * E_DIM + l * 8 + 4];
    float xf[8], s = 0.f, ss = 0.f;
#pragma unroll
    for (int j = 0; j < 8; ++j) {
      xf[j] = (j < 4) ? x0[j] : x1[j - 4];
      s += xf[j];
      ss += xf[j] * xf[j];
    }
#pragma unroll
    for (int off = 32; off > 0; off >>= 1) {
      s += __shfl_xor(s, off);
      ss += __shfl_xor(ss, off);
    }
    float mu = s * (1.f / 512.f);
    float var = fmaxf(ss * (1.f / 512.f) - mu * mu, 0.f);
    float rs = rsqrtf(var + 1e-5f);
    f32x4 g0 = *(const f32x4*)&g[l * 8];
    f32x4 g1 = *(const f32x4*)&g[l * 8 + 4];
    f32x4 b0 = *(const f32x4*)&bb[l * 8];
    f32x4 b1 = *(const f32x4*)&bb[l * 8 + 4];
#pragma unroll
    for (int j = 0; j < 8; ++j) {
      float gv = (j < 4) ? g0[j] : g1[j - 4];
      float bv = (j < 4) ? b0[j] : b1[j - 4];
      y[row * E_DIM + l * 8 + j] = f2b((xf[j] - mu) * rs * gv + bv);
    }
  }
}

// ------------- GEMM core, 128x64 tile, BK=64, 4 waves in 2x2 (each 64x32) -------------
// Smaller N-tile -> 2x the blocks of the old 128x128 (512/GEMM = 2-6 blocks/CU): these
// M=8192,N=512 GEMMs are latency-bound at 1 block/CU, not BW/MFMA-bound. LDS 24KB.
// MODE 0: bf16 row-major C (with scale)  MODE 1: fp32 row-major C
// MODE 2: bf16 Vt-transposed epilogue  Vt[((b*8+h)*64+d)*2048 + k]  (packed uint2 along k)
template <int MODE>
static __device__ __forceinline__ void gemm_core64(ushort_t* lA, ushort_t* lB,
                                                   const ushort_t* __restrict__ A,
                                                   const ushort_t* __restrict__ WT,
                                                   const float* __restrict__ bias,
                                                   void* Cv, float scale, int m0, int n0) {
  int t = threadIdx.x, w = t >> 6, l = t & 63;
  int quad = l >> 4, l15 = l & 15;
  int wm_ = w >> 1, wn_ = w & 1;
  int csrc = ((l & 7) ^ (l >> 3)) * 8;   // swizzle folded into per-lane global column
  int rln = l >> 3;

  f32x4 acc[4][2] = {};
  for (int kk = 0; kk < E_DIM; kk += 64) {
    __syncthreads();
#pragma unroll
    for (int i = 0; i < 4; ++i) {        // A: 128 rows
      int r0 = i * 32 + w * 8;
      gl2lds16(&A[(size_t)(m0 + r0 + rln) * E_DIM + kk + csrc], &lA[r0 * 64]);
    }
#pragma unroll
    for (int i = 0; i < 2; ++i) {        // B: 64 rows
      int r0 = i * 32 + w * 8;
      gl2lds16(&WT[(size_t)(n0 + r0 + rln) * E_DIM + kk + csrc], &lB[r0 * 64]);
    }
    __syncthreads();
#pragma unroll
    for (int ks = 0; ks < 2; ++ks) {
      bf16x8 af[4], bf[2];
#pragma unroll
      for (int mt = 0; mt < 4; ++mt)
        af[mt] = *(const bf16x8*)&lA[swz(wm_ * 64 + mt * 16 + l15, ks * 32 + quad * 8)];
#pragma unroll
      for (int nt = 0; nt < 2; ++nt)
        bf[nt] = *(const bf16x8*)&lB[swz(wn_ * 32 + nt * 16 + l15, ks * 32 + quad * 8)];
#pragma unroll
      for (int mt = 0; mt < 4; ++mt)
#pragma unroll
        for (int nt = 0; nt < 2; ++nt)
          acc[mt][nt] = __builtin_amdgcn_mfma_f32_16x16x32_bf16(af[mt], bf[nt], acc[mt][nt], 0, 0, 0);
    }
  }

#pragma unroll
  for (int nt = 0; nt < 2; ++nt) {
    int col = n0 + wn_ * 32 + nt * 16 + l15;
    float bv = bias[col];
    if constexpr (MODE == 2) {
      int h = col >> 6, d = col & 63;
#pragma unroll
      for (int mt = 0; mt < 4; ++mt) {
        int row = m0 + wm_ * 64 + mt * 16 + quad * 4;   // 4 consecutive k (r=0..3)
        int b = row >> 11, k = row & 2047;
        union { ushort_t u[4]; uint2 v; } pk;
#pragma unroll
        for (int r = 0; r < 4; ++r) pk.u[r] = f2b(acc[mt][nt][r] + bv);
        *(uint2*)&((ushort_t*)Cv)[((((size_t)(b * HEADS + h)) * HD + d) << 11) + k] = pk.v;
      }
    } else {
#pragma unroll
      for (int mt = 0; mt < 4; ++mt) {
#pragma unroll
        for (int r = 0; r < 4; ++r) {
          int rowm = m0 + wm_ * 64 + mt * 16 + quad * 4 + r;   // C/D: col=l&15, row=quad*4+r
          float val = (acc[mt][nt][r] + bv) * scale;
          if constexpr (MODE == 0)
            ((ushort_t*)Cv)[rowm * E_DIM + col] = f2b(val);
          else
            ((float*)Cv)[rowm * E_DIM + col] = val;
        }
      }
    }
  }
}

// Fused projections. Grid = 512*nz blocks, XCD-bijective chunking (n fastest within a
// chunk so the 8 blocks sharing an A row-panel sit on one XCD's L2).
// z = zbase + work/512:  0: qp=(qn@WTq+bq)*QSCALE   1: Vt=T(kvn@WTv+bv)   2: kp=kvn@WTk+bk
__launch_bounds__(256)
__global__ void proj3_kernel(const ushort_t* __restrict__ qn, const ushort_t* __restrict__ WTq,
                             const float* __restrict__ bq, ushort_t* __restrict__ qp,
                             const ushort_t* __restrict__ kvn, const ushort_t* __restrict__ WTv,
                             const float* __restrict__ bv, ushort_t* __restrict__ Vt,
                             const ushort_t* __restrict__ WTk, const float* __restrict__ bk,
                             ushort_t* __restrict__ kp, int zbase) {
  __shared__ ushort_t lA[128 * 64];
  __shared__ ushort_t lB[64 * 64];
  int flat = blockIdx.x;
  int chunk = gridDim.x >> 3;
  int work = (flat & 7) * chunk + (flat >> 3);
  int z = zbase + (work >> 9);
  int r = work & 511;
  int m0 = (r >> 3) * 128, n0 = (r & 7) * 64;
  if (z == 0)      gemm_core64<0>(lA, lB, qn,  WTq, bq, qp, QSCALE, m0, n0);
  else if (z == 1) gemm_core64<2>(lA, lB, kvn, WTv, bv, Vt, 1.f,    m0, n0);
  else             gemm_core64<0>(lA, lB, kvn, WTk, bk, kp, 1.f,    m0, n0);
}

// Output GEMM: ctx@WTo+bo -> fp32. 512 blocks (2/CU), XCD-chunked.
__launch_bounds__(256)
__global__ void out_kernel(const ushort_t* __restrict__ A, const ushort_t* __restrict__ WT,
                           const float* __restrict__ bias, float* __restrict__ C) {
  __shared__ ushort_t lA[128 * 64];
  __shared__ ushort_t lB[64 * 64];
  int flat = blockIdx.x;
  int work = (flat & 7) * 64 + (flat >> 3);
  int m0 = (work >> 3) * 128, n0 = (work & 7) * 64;
  gemm_core64<1>(lA, lB, A, WT, bias, C, 1.f, m0, n0);
}

// ---------------- flash attention: 32x32x16 MFMA, transposed-S, no-max softmax -------------
// q-tile 64, block = 4 waves = (2 q-waves) x (2 k-slices). Partial O/lsum ADDITIVE
// (no-max log2 softmax) -> cross-slice LDS merge at the end. LDS 40KB.
// XCD-bijective swizzle keeps each (b,h) K/V panel on ONE XCD L2 (FETCH 70->14MB in R2).
// S^T = K*Q^T: C col=lane&31 (=q), row=(r&3)+8*(r>>2)+4*half (=k_local). P stays in
// registers via cvt_pk_bf16 + permlane32_swap (T12). Masked scores -> NEGF -> exp2 = 0.
__launch_bounds__(256)
__global__ void attn_kernel(const ushort_t* __restrict__ Qp, const ushort_t* __restrict__ Kp,
                            const ushort_t* __restrict__ Vt,
                            const unsigned long long* __restrict__ bits,
                            ushort_t* __restrict__ ctx) {
  __shared__ __align__(16) char smemb[40960];
  ushort_t* sQ = (ushort_t*)smemb;                       // [0, 8192)
  int t = threadIdx.x, w = t >> 6, l = t & 63;
  int qw = w & 1, ks = w >> 1;
  ushort_t* sK = (ushort_t*)(smemb + 8192 + ks * 8192);  // [8192, 24576)
  ushort_t* sV = (ushort_t*)(smemb + 24576 + ks * 8192); // [24576, 40960)
  int l31 = l & 31, half = l >> 5;

  int flat = blockIdx.x;
  int work = (flat & 7) * 128 + (flat >> 3);   // bijective XCD chunking (1024 = 8*128)
  int qblk = work & 31;
  int h = (work >> 5) & 7;
  int b = work >> 8;
  int q0 = qblk * 64;
  int bh = b * HEADS + h;
  int myq = qw * 32 + l31;
  int csrc = ((l & 7) ^ (l >> 3)) * 8;
  int rln = l >> 3;

  // stage Q (64 rows, all 4 waves), drained by tile 0's second barrier
#pragma unroll
  for (int it = 0; it < 2; ++it) {
    int r0 = w * 16 + it * 8;
    gl2lds16(&Qp[(size_t)(b * SEQ + q0 + r0 + rln) * E_DIM + h * HD + csrc], &sQ[r0 * 64]);
  }

  const unsigned long long* mrow = bits + ((size_t)(b * SEQ + q0 + myq) << 5);
  float ls0 = 0.f, ls1 = 0.f, ls2 = 0.f, ls3 = 0.f;
  f32x16 o0 = {}, o1 = {};
  bf16x8 qf[4];

  for (int t16 = 0; t16 < 16; ++t16) {
    int kt = t16 * 2 + ks;
    int k0 = kt * 64;
    unsigned long long wmask = mrow[kt];
    __syncthreads();   // prev tile's sK/sV reads done (both slices)
    // slice waves (2 per slice) stage this slice's K/V tile: 8 row-groups each of K and V
#pragma unroll
    for (int it = 0; it < 4; ++it) {
      int r0 = (it * 2 + qw) * 8;
      gl2lds16(&Kp[(size_t)(b * SEQ + k0 + r0 + rln) * E_DIM + h * HD + csrc], &sK[r0 * 64]);
      gl2lds16(&Vt[((size_t)bh * HD + r0 + rln) * SEQ + k0 + csrc], &sV[r0 * 64]);
    }
    __syncthreads();   // DMA drained (each wave waits its own vmcnt(0) then barrier)
    if (t16 == 0) {    // cache Q B-fragments: B[d][q]=Q[q][d], d-chunk = ds*16+8*half
#pragma unroll
      for (int ds = 0; ds < 4; ++ds)
        qf[ds] = *(const bf16x8*)&sQ[swz(myq, ds * 16 + 8 * half)];
    }

    // S^T: two 32x32 subtiles (kt2 = k-half), 4 d-steps each
    f32x16 s0 = {}, s1 = {};
    __builtin_amdgcn_s_setprio(1);
#pragma unroll
    for (int ds = 0; ds < 4; ++ds) {
      bf16x8 kf0 = *(const bf16x8*)&sK[swz(l31, ds * 16 + 8 * half)];
      bf16x8 kf1 = *(const bf16x8*)&sK[swz(32 + l31, ds * 16 + 8 * half)];
      s0 = __builtin_amdgcn_mfma_f32_32x32x16_bf16(kf0, qf[ds], s0, 0, 0, 0);
      s1 = __builtin_amdgcn_mfma_f32_32x32x16_bf16(kf1, qf[ds], s1, 0, 0, 0);
    }
    __builtin_amdgcn_s_setprio(0);

    // softmax + in-register P->B-fragment build (no LDS)
    bf16x8 pf[4];
#pragma unroll
    for (int kt2 = 0; kt2 < 2; ++kt2) {
      const f32x16& sv = kt2 ? s1 : s0;
      unsigned h32 = ((unsigned)(wmask >> (32 * kt2))) >> (4 * half);
      unsigned wa[4], wb[4];
#pragma unroll
      for (int g = 0; g < 4; ++g) {
        unsigned gb = h32 >> (8 * g);
        float p0 = fexp2((gb & 1u)        ? sv[g * 4 + 0] : NEGF);  // masked -> exactly 0
        float p1 = fexp2(((gb >> 1) & 1u) ? sv[g * 4 + 1] : NEGF);
        float p2 = fexp2(((gb >> 2) & 1u) ? sv[g * 4 + 2] : NEGF);
        float p3 = fexp2(((gb >> 3) & 1u) ? sv[g * 4 + 3] : NEGF);
        ls0 += p0; ls1 += p1; ls2 += p2; ls3 += p3;
        wa[g] = cvt_pk_bf16(p0, p1);   // pv at k' = 8g+4*half+{0,1}
        wb[g] = cvt_pk_bf16(p2, p3);   // pv at k' = 8g+4*half+{2,3}
      }
      asm("v_permlane32_swap_b32 %0, %1" : "+v"(wa[0]), "+v"(wa[1]));
      asm("v_permlane32_swap_b32 %0, %1" : "+v"(wb[0]), "+v"(wb[1]));
      asm("v_permlane32_swap_b32 %0, %1" : "+v"(wa[2]), "+v"(wa[3]));
      asm("v_permlane32_swap_b32 %0, %1" : "+v"(wb[2]), "+v"(wb[3]));
      union { unsigned u[4]; bf16x8 v; } f0, f1;
      f0.u[0] = wa[0]; f0.u[1] = wb[0]; f0.u[2] = wa[1]; f0.u[3] = wb[1];
      f1.u[0] = wa[2]; f1.u[1] = wb[2]; f1.u[2] = wa[3]; f1.u[3] = wb[3];
      pf[kt2 * 2 + 0] = f0.v;
      pf[kt2 * 2 + 1] = f1.v;
    }

    // O^T += V^T P^T  (P fragments in registers)
    __builtin_amdgcn_s_setprio(1);
#pragma unroll
    for (int ksp = 0; ksp < 4; ++ksp) {
      bf16x8 vf0 = *(const bf16x8*)&sV[swz(l31, ksp * 16 + 8 * half)];
      bf16x8 vf1 = *(const bf16x8*)&sV[swz(32 + l31, ksp * 16 + 8 * half)];
      o0 = __builtin_amdgcn_mfma_f32_32x32x16_bf16(vf0, pf[ksp], o0, 0, 0, 0);
      o1 = __builtin_amdgcn_mfma_f32_32x32x16_bf16(vf1, pf[ksp], o1, 0, 0, 0);
    }
    __builtin_amdgcn_s_setprio(0);
  }

  // within-wave: lanes l and l+32 share q -> one shuffle completes the partial row sum
  float lsum = (ls0 + ls1) + (ls2 + ls3);
  lsum += __shfl_xor(lsum, 32);

  // cross-slice merge: slice 1 writes partials to LDS (K/V area is dead), slice 0 adds.
  __syncthreads();                       // all compute done before overwriting K/V area
  float* mrg = (float*)(smemb + 8192);   // [2 qw][64 lanes][33 floats] = 16.9KB
  if (ks == 1) {
    float* e = mrg + (qw * 64 + l) * 33;
#pragma unroll
    for (int r = 0; r < 16; ++r) e[r] = o0[r];
#pragma unroll
    for (int r = 0; r < 16; ++r) e[16 + r] = o1[r];
    e[32] = lsum;
  }
  __syncthreads();
  if (ks == 0) {
    const float* e = mrg + (qw * 64 + l) * 33;
#pragma unroll
    for (int r = 0; r < 16; ++r) o0[r] += e[r];
#pragma unroll
    for (int r = 0; r < 16; ++r) o1[r] += e[16 + r];
    lsum += e[32];
    float inv = (lsum > 0.f) ? 1.f / lsum : 0.f;   // all-masked row -> 0 (nan_to_num)
    size_t base = (size_t)(b * SEQ + q0 + myq) * E_DIM + h * HD;
#pragma unroll
    for (int dt = 0; dt < 2; ++dt) {
      const f32x16& oo = dt ? o1 : o0;
#pragma unroll
      for (int g = 0; g < 4; ++g) {
        union { ushort_t u[4]; uint2 v; } ov;
#pragma unroll
        for (int r = 0; r < 4; ++r) ov.u[r] = f2b(oo[g * 4 + r] * inv);
        *(uint2*)&ctx[base + dt * 32 + g * 8 + 4 * half] = ov.v;   // d=(r)+8g+4*half+32dt
      }
    }
  }
}

// ---------------- launch ----------------
// fp32 in/out, bf16 internals. d_out (16 MB fp32) = two 8 MB bf16 slots dlo/dhi.
// Preferred (ws >= 28 MiB): bufA(8) bufB(8) WT(2) bits(2) bufC(8):
//   1 prep:  WT, bits, qn->dlo, kvn->bufA
//   2 proj3: qp->dhi, Vt->bufB, kp->bufC   (one dispatch, 1536 blocks = 6/CU)
//   3 attn:  (dhi, bufC, bufB, bits) -> bufA
//   4 out:   bufA@WTo+bo -> d_out fp32
// Fallback (ws < 28 MiB): proj3 split into (q,v) then (k->dlo) like the old schedule.
extern "C" void kernel_launch(void* const* d_in, const int* in_sizes, int n_in,
                              void* d_out, int out_size, void* d_ws, size_t ws_size,
                              hipStream_t stream) {
  const float* query     = (const float*)d_in[0];
  const float* key_value = (const float*)d_in[1];
  const int*   kv_mask   = (const int*)d_in[2];
  const int*   sp_mask   = (const int*)d_in[3];
  const float* ln_q_g  = (const float*)d_in[4];
  const float* ln_q_b  = (const float*)d_in[5];
  const float* ln_kv_g = (const float*)d_in[6];
  const float* ln_kv_b = (const float*)d_in[7];
  const float* Wq = (const float*)d_in[8];
  const float* bq = (const float*)d_in[9];
  const float* Wk = (const float*)d_in[10];
  const float* bk = (const float*)d_in[11];
  const float* Wv = (const float*)d_in[12];
  const float* bv = (const float*)d_in[13];
  const float* Wo = (const float*)d_in[14];
  const float* bo = (const float*)d_in[15];

  const size_t NB = (size_t)NROWS * E_DIM;       // 8 MiB bf16 slot
  char* ws = (char*)d_ws;
  ushort_t* bufA = (ushort_t*)ws;                // kvn -> ctx
  ushort_t* bufB = bufA + NB;                    // Vt
  ushort_t* WT   = bufB + NB;                    // 4 x 512x512 bf16 = 2 MiB
  ushort_t* WTq = WT;
  ushort_t* WTk = WTq + E_DIM * E_DIM;
  ushort_t* WTv = WTk + E_DIM * E_DIM;
  ushort_t* WTo = WTv + E_DIM * E_DIM;
  unsigned long long* bits = (unsigned long long*)(WTo + E_DIM * E_DIM);  // 2 MiB
  ushort_t* bufC = (ushort_t*)(ws + (20u << 20));                         // kp (8 MiB)

  ushort_t* dlo = (ushort_t*)d_out;              // qn, then (fallback) kp
  ushort_t* dhi = dlo + NB;                      // qp

  bool fused = ws_size >= (28u << 20);
  ushort_t* kp = fused ? bufC : dlo;

  prep_kernel<<<7168, 256, 0, stream>>>(Wq, Wk, Wv, Wo, WT, kv_mask, sp_mask, bits,
                                        query, key_value, ln_q_g, ln_q_b, ln_kv_g, ln_kv_b,
                                        dlo, bufA);

  if (fused) {
    proj3_kernel<<<1536, 256, 0, stream>>>(dlo, WTq, bq, dhi,
                                           bufA, WTv, bv, bufB,
                                           WTk, bk, bufC, 0);
  } else {
    proj3_kernel<<<1024, 256, 0, stream>>>(dlo, WTq, bq, dhi,
                                           bufA, WTv, bv, bufB,
                                           WTk, bk, dlo, 0);       // z in {0,1}: kp unused
    proj3_kernel<<<512, 256, 0, stream>>>(dlo, WTq, bq, dhi,
                                          bufA, WTv, bv, bufB,
                                          WTk, bk, dlo, 2);        // z = 2: kp -> dlo
  }

  attn_kernel<<<1024, 256, 0, stream>>>(dhi, kp, bufB, bits, bufA);

  out_kernel<<<512, 256, 0, stream>>>(bufA, WTo, bo, (float*)d_out);
}